// Round 1
// baseline (110.460 us; speedup 1.0000x reference)
//
#include <hip/hip_runtime.h>
#include <math.h>

#define V_SZ 100000
#define D_SZ 64
#define B_SZ 4096
#define L_SZ 50
#define K_SZ 3
#define MAX_NORM 20.0f

// Kernel 1: per-row renorm scale factor. 16 lanes per row, float4 loads.
__global__ __launch_bounds__(256) void renorm_scale_kernel(
    const float* __restrict__ emb, float* __restrict__ scale) {
    int row = blockIdx.x * 16 + (threadIdx.x >> 4);
    int lane16 = threadIdx.x & 15;
    if (row >= V_SZ) return;
    const float4* row4 = (const float4*)(emb + (long)row * D_SZ);
    float4 v = row4[lane16];
    float ss = v.x * v.x + v.y * v.y + v.z * v.z + v.w * v.w;
    // butterfly reduce across the 16 lanes of this row
    #pragma unroll
    for (int off = 8; off >= 1; off >>= 1)
        ss += __shfl_xor(ss, off, 16);
    if (lane16 == 0) {
        float n = sqrtf(ss);
        scale[row] = (n > MAX_NORM) ? (MAX_NORM / n) : 1.0f;
    }
}

// Kernel 2: one wave64 per output bag; lane = embedding dim.
// Bag o: o<B -> tokens_l row o; o<2B -> tokens_r row o-B; else tokens_neg row o-2B.
// Output layout is exactly out[o*D + lane] (l | r | neg concatenated).
__global__ __launch_bounds__(256) void embed_bag_kernel(
    const float* __restrict__ emb, const float* __restrict__ scale,
    const int* __restrict__ tl, const int* __restrict__ tr,
    const int* __restrict__ tn, float* __restrict__ out) {
    const int NBAGS = B_SZ * (2 + K_SZ);
    int wave = (int)((blockIdx.x * (unsigned)blockDim.x + threadIdx.x) >> 6);
    int lane = threadIdx.x & 63;
    if (wave >= NBAGS) return;

    const int* tok;
    if (wave < B_SZ)            tok = tl + (long)wave * L_SZ;
    else if (wave < 2 * B_SZ)   tok = tr + (long)(wave - B_SZ) * L_SZ;
    else                        tok = tn + (long)(wave - 2 * B_SZ) * L_SZ;

    // lane j (< L) holds token j and its scale; broadcast via shfl in the loop
    int   t = (lane < L_SZ) ? tok[lane] : 0;
    float s = (lane < L_SZ) ? scale[t] : 0.0f;

    float acc = 0.0f;
    #pragma unroll
    for (int j = 0; j < L_SZ; ++j) {
        int   tj = __shfl(t, j);
        float sj = __shfl(s, j);
        acc = fmaf(sj, emb[(long)tj * D_SZ + lane], acc);
    }
    out[(long)wave * D_SZ + lane] = acc;
}

extern "C" void kernel_launch(void* const* d_in, const int* in_sizes, int n_in,
                              void* d_out, int out_size, void* d_ws, size_t ws_size,
                              hipStream_t stream) {
    const float* emb = (const float*)d_in[0];
    const int* tl = (const int*)d_in[1];
    const int* tr = (const int*)d_in[2];
    const int* tn = (const int*)d_in[3];
    float* out = (float*)d_out;
    float* scale = (float*)d_ws;  // V_SZ floats = 400 KB scratch

    // 1) scales (d_ws is re-poisoned every call; we rewrite it fully each call)
    renorm_scale_kernel<<<(V_SZ + 15) / 16, 256, 0, stream>>>(emb, scale);

    // 2) gather + sum-pool, one wave per bag
    const int NBAGS = B_SZ * (2 + K_SZ);            // 20480
    const int waves_per_block = 4;                  // 256 threads
    int grid = (NBAGS + waves_per_block - 1) / waves_per_block;  // 5120
    embed_bag_kernel<<<grid, 256, 0, stream>>>(emb, scale, tl, tr, tn, out);
}